// Round 11
// baseline (785.228 us; speedup 1.0000x reference)
//
#include <hip/hip_runtime.h>
#include <math.h>

#define B_SZ 1024
#define T_SZ 512
#define C_CH 65
#define HID  160
#define OUTD 32
#define M_ELEM 8
#define NBLK 128          // B_SZ / M_ELEM
#define NTHR 640          // 10 waves
#define HBUF_DW 800       // dwords per h parity buffer

#define LOG2E 1.4426950408889634f

// workspace layout (bytes)
#define OBS_OFF 0                    // 1024*512 = 512KB
#define ANY_OFF  524288              // 2KB
#define XD0_OFF  526336              // 2MB
#define S_OFF    2623488             // 4MB
#define WHH_OFF  6817792             // 153600B
#define WIH_OFF  6971392             // 30720B

typedef float f32x4_t __attribute__((ext_vector_type(4)));
typedef float f32x2_t __attribute__((ext_vector_type(2)));
typedef short bf16x8_t __attribute__((ext_vector_type(8)));
typedef unsigned u32x2_t __attribute__((ext_vector_type(2)));
typedef unsigned u32x4_t __attribute__((ext_vector_type(4)));
union frag_u { u32x4_t u; bf16x8_t h; };

__device__ __forceinline__ unsigned short f2bf(float x) {
  unsigned int u = __float_as_uint(x);
  unsigned int r = ((u >> 16) & 1u) + 0x7FFFu;
  return (unsigned short)((u + r) >> 16);
}
__device__ __forceinline__ unsigned cvt_pk_bf16(float lo, float hi) {
  unsigned r;
  asm("v_cvt_pk_bf16_f32 %0, %1, %2" : "=v"(r) : "v"(lo), "v"(hi));
  return r;
}
__device__ __forceinline__ float exp2_f(float x) {
  float r; asm("v_exp_f32 %0, %1" : "=v"(r) : "v"(x)); return r;
}
__device__ __forceinline__ float rcp_f(float x) {
  float r; asm("v_rcp_f32 %0, %1" : "=v"(r) : "v"(x)); return r;
}
__device__ __forceinline__ f32x2_t lo2(f32x4_t v) {
  return __builtin_shufflevector(v, v, 0, 1);
}
// non-affine row offset: banks of (row, group) reads are 2-way max
__device__ __forceinline__ int tabf(int r) {
  return ((r & 1) << 1) | (((r >> 1) & 1) << 4) | (((r >> 2) & 1) << 3);
}

// ---------------- phase 0: zero any-flags ----------------
__global__ void k_zero(unsigned* __restrict__ anyv) {
  int i = blockIdx.x * blockDim.x + threadIdx.x;
  if (i < T_SZ) anyv[i] = 0u;
}

// ---------------- phase 1: obs + any + Xd0 ----------------
__global__ __launch_bounds__(256) void k_prep(const float* __restrict__ X,
                                              const float* __restrict__ times,
                                              unsigned char* __restrict__ obs,
                                              unsigned* __restrict__ anyv,
                                              float* __restrict__ xd0) {
  const int b = blockIdx.x;
  const float* Xb = X + (size_t)b * T_SZ * C_CH;
  for (int t = threadIdx.x; t < T_SZ; t += 256) {
    const float* cur = Xb + t * C_CH;
    const float* prv = cur - C_CH;
    float m = -1e30f;
    if (t == 0) {
      #pragma unroll
      for (int c = 1; c <= 32; ++c) m = fmaxf(m, cur[c]);
    } else {
      #pragma unroll
      for (int c = 1; c <= 32; ++c) m = fmaxf(m, cur[c] - prv[c]);
    }
    unsigned char o = (m > 0.5f) ? (unsigned char)1 : (unsigned char)0;
    obs[(size_t)b * T_SZ + t] = o;
    if (o) atomicOr(&anyv[t], 1u);
    xd0[(size_t)b * T_SZ + t] = cur[0] - times[(t == 0) ? 0 : (t - 1)];
  }
}

// ---------------- phase 1b: per-element dt prefix + flag table -----------
__global__ __launch_bounds__(64) void k_dt(const unsigned char* __restrict__ obs,
                                           const unsigned* __restrict__ anyv,
                                           const float* __restrict__ xd0,
                                           const int* __restrict__ fidx,
                                           float2* __restrict__ S) {
  const int b = blockIdx.x;
  const int lane = threadIdx.x;
  const int t0 = lane * 8;
  const unsigned long long o8 =
      *(const unsigned long long*)(obs + (size_t)b * T_SZ + t0);
  const float4* xd4 = (const float4*)(xd0 + (size_t)b * T_SZ + t0);
  const float4 xa = xd4[0], xb = xd4[1];
  const uint4* av4 = (const uint4*)(anyv + t0);
  const uint4 aa = av4[0], ab = av4[1];
  const int fi = fidx[b];
  const float xv[8] = {xa.x, xa.y, xa.z, xa.w, xb.x, xb.y, xb.z, xb.w};
  const unsigned av[8] = {aa.x, aa.y, aa.z, aa.w, ab.x, ab.y, ab.z, ab.w};
  float run = 0.f;
  float dtl[8], fl[8];
  #pragma unroll
  for (int j = 0; j < 8; ++j) {
    const int o = (int)((o8 >> (8 * j)) & 0xffULL);
    const int any = (int)av[j];
    dtl[j] = run;
    if (any && !o) run += xv[j];
    fl[j] = (any && o && (t0 + j) <= fi) ? 1.f : 0.f;
  }
  float inc = run;
  #pragma unroll
  for (int off = 1; off < 64; off <<= 1) {
    float u = __shfl_up(inc, off, 64);
    if (lane >= off) inc += u;
  }
  const float excl = inc - run;
  #pragma unroll
  for (int j = 0; j < 8; ++j)
    S[(size_t)(t0 + j) * B_SZ + b] = make_float2(excl + dtl[j], fl[j]);
}

// ---------------- phase 1c: pack PRESCALED weights into bf16 B-frags -----
__global__ __launch_bounds__(256) void k_pack(const float* __restrict__ w_ih,
                                              const float* __restrict__ w_hh,
                                              unsigned short* __restrict__ whh_f,
                                              unsigned short* __restrict__ wih_f) {
  int i = blockIdx.x * 256 + threadIdx.x;
  if (i < 9600) {
    int l = i & 63; int kt = (i >> 6) % 5; int g = (i / 320) % 3; int q = i / 960;
    const float scl = (g < 2) ? -LOG2E : -2.f * LOG2E;
    int row = g * 160 + q * 16 + (l & 15);
    const float* src = w_hh + (size_t)row * HID + kt * 32 + (l >> 4) * 8;
    unsigned short* dst = whh_f + (size_t)i * 8;
    #pragma unroll
    for (int j = 0; j < 8; ++j) dst[j] = f2bf(scl * src[j]);
  } else if (i < 11520) {
    int i2 = i - 9600;
    int l = i2 & 63; int g = (i2 >> 6) % 3; int q = i2 / 192;
    const float scl = (g < 2) ? -LOG2E : -2.f * LOG2E;
    int row = g * 160 + q * 16 + (l & 15);
    const float* src = w_ih + (size_t)row * 32 + (l >> 4) * 8;
    unsigned short* dst = wih_f + (size_t)i2 * 8;
    #pragma unroll
    for (int j = 0; j < 8; ++j) dst[j] = f2bf(scl * src[j]);
  }
}

#define MFMA16 __builtin_amdgcn_mfma_f32_16x16x32_bf16

// ---------------- phase 2: batched MFMA recurrence ------------------------
// 2-deep global prefetch consumed AFTER the barrier (raw s_barrier +
// lgkmcnt(0) only -> vmcnt stays in flight across steps, T3/T4 style).
// h exchange via non-affine-offset LDS rows (2-way max bank aliasing).
__global__ __launch_bounds__(NTHR) void k_scan(
    const float* __restrict__ X, const int* __restrict__ fidx,
    const float* __restrict__ w_ih,
    const float* __restrict__ b_ih, const float* __restrict__ b_hh,
    const float* __restrict__ lin_w, const float* __restrict__ lin_b,
    const float* __restrict__ Sfp,
    const unsigned short* __restrict__ whh_f, const unsigned short* __restrict__ wih_f,
    float* __restrict__ out)
{
  const int b0 = blockIdx.x * M_ELEM;
  const int tid = threadIdx.x;
  const int wid = tid >> 6;
  const int lane = tid & 63;
  const int q = wid;

  __shared__ __align__(16) unsigned short hbuf[2][HBUF_DW * 2];
  __shared__ __align__(16) float hm[M_ELEM][HID];

  { unsigned* hz = (unsigned*)hbuf;
    for (int i = tid; i < 2 * HBUF_DW; i += NTHR) hz[i] = 0u; }

  int maxfi = 0;
  #pragma unroll
  for (int e = 0; e < M_ELEM; ++e) maxfi = max(maxfi, fidx[b0 + e]);

  // A-frag row -> element map (rows 8-15 permuted duplicates)
  const int r16 = lane & 15;
  const int elA = (r16 < 8) ? r16 : ((r16 & 4) | ((r16 & 3) ^ 2));
  const int mA = ((lane >> 4) & 1) * 4 + ((lane >> 5) & 1) * 2;
  const int mB = mA + 1;
  const int g4 = lane >> 4;

  // LDS addresses (u16 units)
  const int rb_u16 = (elA * 96 + tabf(elA) + g4 * 4) * 2;            // read base
  const int col = q * 16 + r16;
  const int wA = (mA * 96 + tabf(mA) + (col >> 5) * 16 + ((col >> 3) & 3) * 4) * 2
                 + (col & 7);                                        // write base; +196 = row mB

  // ---- resident weight fragments ----
  bf16x8_t whh_v[3][5];
  bf16x8_t wih_v[3];
  #pragma unroll
  for (int g = 0; g < 3; ++g) {
    #pragma unroll
    for (int kt = 0; kt < 5; ++kt)
      whh_v[g][kt] = *(const bf16x8_t*)(whh_f + ((size_t)((q * 3 + g) * 5 + kt) * 64 + lane) * 8);
    wih_v[g] = *(const bf16x8_t*)(wih_f + ((size_t)(q * 3 + g) * 64 + lane) * 8);
  }
  const float b_r  = -LOG2E * (b_ih[col] + b_hh[col]);
  const float b_z  = -LOG2E * (b_ih[160 + col] + b_hh[160 + col]);
  const float b_ni = -2.f * LOG2E * b_ih[320 + col];
  const float b_nh = -2.f * LOG2E * b_hh[320 + col];
  const float w0r = -LOG2E * w_ih[(size_t)col * 32];
  const float w0z = -LOG2E * w_ih[(size_t)(160 + col) * 32];
  const float w0n = -2.f * LOG2E * w_ih[(size_t)(320 + col) * 32];
  const f32x2_t bnh2 = {b_nh, b_nh};

  f32x2_t h2 = {0.f, 0.f};
  const f32x4_t z4 = {0.f, 0.f, 0.f, 0.f};

  const float* xrow_base =
      X + ((size_t)(b0 + elA) * T_SZ) * C_CH + 33 + (g4 * 8);

  // ---- prologue ----
  bf16x8_t xf;
  f32x2_t cr, cz, cn, fl2;
  {
    float x0r[8];
    #pragma unroll
    for (int j = 0; j < 8; ++j) x0r[j] = xrow_base[j];
    unsigned* xu = (unsigned*)&xf;
    #pragma unroll
    for (int j = 0; j < 4; ++j) xu[j] = cvt_pk_bf16(x0r[2 * j], x0r[2 * j + 1]);
    const float4 s0 = *(const float4*)(Sfp + (size_t)(b0 + mA) * 2);
    cr = (f32x2_t){fmaf(s0.x, w0r, b_r), fmaf(s0.z, w0r, b_r)};
    cz = (f32x2_t){fmaf(s0.x, w0z, b_z), fmaf(s0.z, w0z, b_z)};
    cn = (f32x2_t){fmaf(s0.x, w0n, b_ni), fmaf(s0.z, w0n, b_ni)};
    fl2 = (f32x2_t){s0.y, s0.w};
  }
  // issue loads for t=1 (consumed at step 0, after the first barrier region)
  const float* xp = xrow_base + (size_t)((maxfi >= 1) ? 1 : 0) * C_CH;
  const float* sp = Sfp + (size_t)B_SZ * 2 + (size_t)(b0 + mA) * 2;
  float xn[8];
  #pragma unroll
  for (int j = 0; j < 8; ++j) xn[j] = xp[j];
  float4 sreg = *(const float4*)sp;
  __syncthreads();

  const int NSTEP = (maxfi + 2) & ~1;

  auto STEP = [&](int t, int p) {
    // 1. gin MFMAs (xf converted one step ago)
    f32x4_t ginr = MFMA16(xf, wih_v[0], z4, 0, 0, 0);
    f32x4_t ginz = MFMA16(xf, wih_v[1], z4, 0, 0, 0);
    f32x4_t ginn = MFMA16(xf, wih_v[2], z4, 0, 0, 0);

    // 2. h A-frag reads (5 x 2 b64, 8B-aligned, <=2-way banks)
    frag_u hf0, hf1, hf2, hf3, hf4;
    {
      const u32x2_t* hp = (const u32x2_t*)&hbuf[p][rb_u16];
      u32x2_t l0 = hp[0],  u0 = hp[1];
      u32x2_t l1 = hp[8],  u1 = hp[9];
      u32x2_t l2 = hp[16], u2 = hp[17];
      u32x2_t l3 = hp[24], u3 = hp[25];
      u32x2_t l4 = hp[32], u4 = hp[33];
      hf0.u = (u32x4_t){l0.x, l0.y, u0.x, u0.y};
      hf1.u = (u32x4_t){l1.x, l1.y, u1.x, u1.y};
      hf2.u = (u32x4_t){l2.x, l2.y, u2.x, u2.y};
      hf3.u = (u32x4_t){l3.x, l3.y, u3.x, u3.y};
      hf4.u = (u32x4_t){l4.x, l4.y, u4.x, u4.y};
    }

    // 3. consume prefetched x/S (vmcnt latency hidden across the barrier)
    bf16x8_t xf2;
    {
      unsigned* xu = (unsigned*)&xf2;
      #pragma unroll
      for (int j = 0; j < 4; ++j) xu[j] = cvt_pk_bf16(xn[2 * j], xn[2 * j + 1]);
    }
    const f32x2_t crN = {fmaf(sreg.x, w0r, b_r), fmaf(sreg.z, w0r, b_r)};
    const f32x2_t czN = {fmaf(sreg.x, w0z, b_z), fmaf(sreg.z, w0z, b_z)};
    const f32x2_t cnN = {fmaf(sreg.x, w0n, b_ni), fmaf(sreg.z, w0n, b_ni)};
    const f32x2_t flN = {sreg.y, sreg.w};

    // 4. issue loads for t+2 (uniform SALU pointer advance)
    xp += (t + 2 <= maxfi) ? C_CH : 0;
    sp += (t + 2 <= T_SZ - 1) ? B_SZ * 2 : 0;
    #pragma unroll
    for (int j = 0; j < 8; ++j) xn[j] = xp[j];
    sreg = *(const float4*)sp;

    // 5. 15 hh MFMAs, gin as C-input, 6 parallel chains
    __builtin_amdgcn_s_setprio(1);
    f32x4_t ra  = MFMA16(hf0.h, whh_v[0][0], ginr, 0, 0, 0);
    f32x4_t za  = MFMA16(hf0.h, whh_v[1][0], ginz, 0, 0, 0);
    f32x4_t nha = MFMA16(hf0.h, whh_v[2][0], z4,   0, 0, 0);
    f32x4_t rb  = MFMA16(hf2.h, whh_v[0][2], z4,   0, 0, 0);
    f32x4_t zb  = MFMA16(hf2.h, whh_v[1][2], z4,   0, 0, 0);
    f32x4_t nhb = MFMA16(hf3.h, whh_v[2][3], z4,   0, 0, 0);
    ra  = MFMA16(hf1.h, whh_v[0][1], ra,  0, 0, 0);
    za  = MFMA16(hf1.h, whh_v[1][1], za,  0, 0, 0);
    nha = MFMA16(hf1.h, whh_v[2][1], nha, 0, 0, 0);
    rb  = MFMA16(hf3.h, whh_v[0][3], rb,  0, 0, 0);
    zb  = MFMA16(hf3.h, whh_v[1][3], zb,  0, 0, 0);
    nhb = MFMA16(hf4.h, whh_v[2][4], nhb, 0, 0, 0);
    nha = MFMA16(hf2.h, whh_v[2][2], nha, 0, 0, 0);
    rb  = MFMA16(hf4.h, whh_v[0][4], rb,  0, 0, 0);
    zb  = MFMA16(hf4.h, whh_v[1][4], zb,  0, 0, 0);
    __builtin_amdgcn_s_setprio(0);

    // 6. combine + publish h
    {
      const f32x2_t pr = lo2(ra) + lo2(rb) + cr;
      const f32x2_t pz = lo2(za) + lo2(zb) + cz;
      const f32x2_t ph = lo2(nha) + lo2(nhb) + bnh2;
      const f32x2_t pni = lo2(ginn) + cn;
      const f32x2_t rr = {rcp_f(1.f + exp2_f(pr.x)), rcp_f(1.f + exp2_f(pr.y))};
      const f32x2_t zz = {rcp_f(1.f + exp2_f(pz.x)), rcp_f(1.f + exp2_f(pz.y))};
      f32x2_t u = pni + rr * ph;
      u.x = fminf(u.x, 60.f); u.y = fminf(u.y, 60.f);
      const f32x2_t e = {exp2_f(u.x), exp2_f(u.y)};
      const f32x2_t nn = ((f32x2_t){1.f, 1.f} - e) *
                         (f32x2_t){rcp_f(1.f + e.x), rcp_f(1.f + e.y)};
      const f32x2_t upd = nn + zz * (h2 - nn);
      h2 = h2 + fl2 * (upd - h2);
      const unsigned hw = cvt_pk_bf16(h2.x, h2.y);
      unsigned short* wp = &hbuf[p ^ 1][wA];
      wp[0]   = (unsigned short)hw;
      wp[196] = (unsigned short)(hw >> 16);   // row mB (= mA+1): +98 dwords
    }

    // 7. roll pipeline registers (SSA-renamed by unrolled pair)
    xf = xf2; cr = crN; cz = czN; cn = cnN; fl2 = flN;

    // 8. LDS-only barrier: globals stay in flight across it
    asm volatile("s_waitcnt lgkmcnt(0)" ::: "memory");
    __builtin_amdgcn_s_barrier();
    __builtin_amdgcn_sched_barrier(0);
  };

  for (int t = 0; t < NSTEP; t += 2) {
    STEP(t, 0);
    STEP(t + 1, 1);
  }

  // ---- epilogue: h -> LDS, then out = lin_w @ h + lin_b ----
  hm[mA][col] = h2.x;
  hm[mB][col] = h2.y;
  __syncthreads();
  if (tid < 256) {
    const int e = tid >> 5, o = tid & 31;
    const float4* lw = (const float4*)(lin_w + o * HID);
    const float4* hv = (const float4*)(&hm[e][0]);
    float a0 = 0.f, a1 = 0.f, a2 = 0.f, a3 = 0.f;
    #pragma unroll
    for (int k = 0; k < HID / 4; ++k) {
      float4 w = lw[k], h = hv[k];
      a0 = fmaf(w.x, h.x, a0); a1 = fmaf(w.y, h.y, a1);
      a2 = fmaf(w.z, h.z, a2); a3 = fmaf(w.w, h.w, a3);
    }
    out[(size_t)(b0 + e) * OUTD + o] = lin_b[o] + (a0 + a1) + (a2 + a3);
  }
}

extern "C" void kernel_launch(void* const* d_in, const int* in_sizes, int n_in,
                              void* d_out, int out_size, void* d_ws, size_t ws_size,
                              hipStream_t stream) {
  const float* times = (const float*)d_in[0];
  const float* X     = (const float*)d_in[1];
  const int*   fidx  = (const int*)d_in[2];
  const float* w_ih  = (const float*)d_in[3];
  const float* w_hh  = (const float*)d_in[4];
  const float* b_ih  = (const float*)d_in[5];
  const float* b_hh  = (const float*)d_in[6];
  const float* lin_w = (const float*)d_in[7];
  const float* lin_b = (const float*)d_in[8];
  float* outp = (float*)d_out;

  unsigned char* obsb = (unsigned char*)d_ws + OBS_OFF;
  unsigned* anyv = (unsigned*)((char*)d_ws + ANY_OFF);
  float* xd0 = (float*)((char*)d_ws + XD0_OFF);
  float2* S = (float2*)((char*)d_ws + S_OFF);
  unsigned short* whh_f = (unsigned short*)((char*)d_ws + WHH_OFF);
  unsigned short* wih_f = (unsigned short*)((char*)d_ws + WIH_OFF);

  k_zero<<<1, 512, 0, stream>>>(anyv);
  k_prep<<<B_SZ, 256, 0, stream>>>(X, times, obsb, anyv, xd0);
  k_dt<<<B_SZ, 64, 0, stream>>>(obsb, anyv, xd0, fidx, S);
  k_pack<<<45, 256, 0, stream>>>(w_ih, w_hh, whh_f, wih_f);
  k_scan<<<NBLK, NTHR, 0, stream>>>(X, fidx, w_ih, b_ih, b_hh,
                                    lin_w, lin_b, (const float*)S,
                                    whh_f, wih_f, outp);
}

// Round 12
// 559.093 us; speedup vs baseline: 1.4045x; 1.4045x over previous
//
#include <hip/hip_runtime.h>
#include <math.h>

#define B_SZ 1024
#define T_SZ 512
#define C_CH 65
#define HID  160
#define OUTD 32
#define M_ELEM 4
#define NBLK 256          // B_SZ / M_ELEM -> one block per CU
#define NTHR 640          // 10 waves

#define LOG2E 1.4426950408889634f

// workspace layout (bytes)
#define OBS_OFF 0                    // 1024*512 = 512KB
#define ANY_OFF  524288              // 2KB
#define XD0_OFF  526336              // 2MB
#define S_OFF    2623488             // 4MB
#define WHH_OFF  6817792             // 153600B
#define WIH_OFF  6971392             // 30720B

typedef float f32x4_t __attribute__((ext_vector_type(4)));
typedef short bf16x8_t __attribute__((ext_vector_type(8)));
typedef unsigned u32x2_t __attribute__((ext_vector_type(2)));
typedef unsigned u32x4_t __attribute__((ext_vector_type(4)));
union frag_u { u32x4_t u; bf16x8_t h; };

__device__ __forceinline__ unsigned short f2bf(float x) {
  unsigned int u = __float_as_uint(x);
  unsigned int r = ((u >> 16) & 1u) + 0x7FFFu;
  return (unsigned short)((u + r) >> 16);
}
__device__ __forceinline__ unsigned cvt_pk_bf16(float lo, float hi) {
  unsigned r;
  asm("v_cvt_pk_bf16_f32 %0, %1, %2" : "=v"(r) : "v"(lo), "v"(hi));
  return r;
}
__device__ __forceinline__ float exp2_f(float x) {
  float r; asm("v_exp_f32 %0, %1" : "=v"(r) : "v"(x)); return r;
}
__device__ __forceinline__ float rcp_f(float x) {
  float r; asm("v_rcp_f32 %0, %1" : "=v"(r) : "v"(x)); return r;
}
// non-affine row offset (dwords): rows 0..3 -> {0,2,16,18}; with stride 96
// the 16 (elem,g4) b64-pair read addresses land on 16 distinct banks and
// 4-lane same-address broadcast makes reads conflict-free (validated r11).
__device__ __forceinline__ int tabf(int r) {
  return ((r & 1) << 1) | (((r >> 1) & 1) << 4);
}

// ---------------- phase 0: zero any-flags ----------------
__global__ void k_zero(unsigned* __restrict__ anyv) {
  int i = blockIdx.x * blockDim.x + threadIdx.x;
  if (i < T_SZ) anyv[i] = 0u;
}

// ---------------- phase 1: obs + any + Xd0 ----------------
__global__ __launch_bounds__(256) void k_prep(const float* __restrict__ X,
                                              const float* __restrict__ times,
                                              unsigned char* __restrict__ obs,
                                              unsigned* __restrict__ anyv,
                                              float* __restrict__ xd0) {
  const int b = blockIdx.x;
  const float* Xb = X + (size_t)b * T_SZ * C_CH;
  for (int t = threadIdx.x; t < T_SZ; t += 256) {
    const float* cur = Xb + t * C_CH;
    const float* prv = cur - C_CH;
    float m = -1e30f;
    if (t == 0) {
      #pragma unroll
      for (int c = 1; c <= 32; ++c) m = fmaxf(m, cur[c]);
    } else {
      #pragma unroll
      for (int c = 1; c <= 32; ++c) m = fmaxf(m, cur[c] - prv[c]);
    }
    unsigned char o = (m > 0.5f) ? (unsigned char)1 : (unsigned char)0;
    obs[(size_t)b * T_SZ + t] = o;
    if (o) atomicOr(&anyv[t], 1u);
    xd0[(size_t)b * T_SZ + t] = cur[0] - times[(t == 0) ? 0 : (t - 1)];
  }
}

// ---------------- phase 1b: per-element dt prefix + flag table -----------
__global__ __launch_bounds__(64) void k_dt(const unsigned char* __restrict__ obs,
                                           const unsigned* __restrict__ anyv,
                                           const float* __restrict__ xd0,
                                           const int* __restrict__ fidx,
                                           float2* __restrict__ S) {
  const int b = blockIdx.x;
  const int lane = threadIdx.x;
  const int t0 = lane * 8;
  const unsigned long long o8 =
      *(const unsigned long long*)(obs + (size_t)b * T_SZ + t0);
  const float4* xd4 = (const float4*)(xd0 + (size_t)b * T_SZ + t0);
  const float4 xa = xd4[0], xb = xd4[1];
  const uint4* av4 = (const uint4*)(anyv + t0);
  const uint4 aa = av4[0], ab = av4[1];
  const int fi = fidx[b];
  const float xv[8] = {xa.x, xa.y, xa.z, xa.w, xb.x, xb.y, xb.z, xb.w};
  const unsigned av[8] = {aa.x, aa.y, aa.z, aa.w, ab.x, ab.y, ab.z, ab.w};
  float run = 0.f;
  float dtl[8], fl[8];
  #pragma unroll
  for (int j = 0; j < 8; ++j) {
    const int o = (int)((o8 >> (8 * j)) & 0xffULL);
    const int any = (int)av[j];
    dtl[j] = run;
    if (any && !o) run += xv[j];
    fl[j] = (any && o && (t0 + j) <= fi) ? 1.f : 0.f;
  }
  float inc = run;
  #pragma unroll
  for (int off = 1; off < 64; off <<= 1) {
    float u = __shfl_up(inc, off, 64);
    if (lane >= off) inc += u;
  }
  const float excl = inc - run;
  #pragma unroll
  for (int j = 0; j < 8; ++j)
    S[(size_t)(t0 + j) * B_SZ + b] = make_float2(excl + dtl[j], fl[j]);
}

// ---------------- phase 1c: pack PRESCALED weights into bf16 B-frags -----
__global__ __launch_bounds__(256) void k_pack(const float* __restrict__ w_ih,
                                              const float* __restrict__ w_hh,
                                              unsigned short* __restrict__ whh_f,
                                              unsigned short* __restrict__ wih_f) {
  int i = blockIdx.x * 256 + threadIdx.x;
  if (i < 9600) {
    int l = i & 63; int kt = (i >> 6) % 5; int g = (i / 320) % 3; int q = i / 960;
    const float scl = (g < 2) ? -LOG2E : -2.f * LOG2E;
    int row = g * 160 + q * 16 + (l & 15);
    const float* src = w_hh + (size_t)row * HID + kt * 32 + (l >> 4) * 8;
    unsigned short* dst = whh_f + (size_t)i * 8;
    #pragma unroll
    for (int j = 0; j < 8; ++j) dst[j] = f2bf(scl * src[j]);
  } else if (i < 11520) {
    int i2 = i - 9600;
    int l = i2 & 63; int g = (i2 >> 6) % 3; int q = i2 / 192;
    const float scl = (g < 2) ? -LOG2E : -2.f * LOG2E;
    int row = g * 160 + q * 16 + (l & 15);
    const float* src = w_ih + (size_t)row * 32 + (l >> 4) * 8;
    unsigned short* dst = wih_f + (size_t)i2 * 8;
    #pragma unroll
    for (int j = 0; j < 8; ++j) dst[j] = f2bf(scl * src[j]);
  }
}

#define MFMA16 __builtin_amdgcn_mfma_f32_16x16x32_bf16

// ---------------- phase 2: batched MFMA recurrence ------------------------
// 4 elements/block, 256 blocks (all CUs), 10 waves; wave q owns 16 gate-cols
// x 3 gates (18 MFMA). A-frag row r holds element ((r>>2)+(r&3))&3, so acc
// reg 0 of EVERY lane is a unique real (element=g4, col) pair: combine is
// ONE entry per lane, one ds_write_b16. LDS h exchange uses the r11-validated
// tabf bank layout (reads broadcast, conflict-free). r10's proven
// __syncthreads() loop structure (no asm barriers / sched pinning).
__global__ __launch_bounds__(NTHR) void k_scan(
    const float* __restrict__ X, const int* __restrict__ fidx,
    const float* __restrict__ w_ih,
    const float* __restrict__ b_ih, const float* __restrict__ b_hh,
    const float* __restrict__ lin_w, const float* __restrict__ lin_b,
    const float2* __restrict__ Sf,
    const unsigned short* __restrict__ whh_f, const unsigned short* __restrict__ wih_f,
    float* __restrict__ out)
{
  const int b0 = blockIdx.x * M_ELEM;
  const int tid = threadIdx.x;
  const int wid = tid >> 6;
  const int lane = tid & 63;
  const int q = wid;

  __shared__ __align__(16) unsigned short hbuf[2][800];   // bf16 h dbuf (tabf rows)
  __shared__ __align__(16) float hm[M_ELEM][HID];

  { unsigned* hz = (unsigned*)hbuf;
    for (int i = tid; i < 800; i += NTHR) hz[i] = 0u; }

  int maxfi = 0;
  #pragma unroll
  for (int e = 0; e < M_ELEM; ++e) maxfi = max(maxfi, fidx[b0 + e]);

  const int r16 = lane & 15;
  const int g4 = lane >> 4;
  // A-frag row -> element (permuted duplication)
  const int elA = ((r16 >> 2) + (r16 & 3)) & 3;
  // combine element: acc reg 0 = row 4*g4 -> element g4
  const int me = g4;

  // LDS addresses
  const int rb_u16 = (elA * 96 + tabf(elA)) * 2 + g4 * 8;          // read base (u16)
  const int col = q * 16 + r16;
  const int wA_u16 = (g4 * 96 + tabf(g4)) * 2 + col;               // write (u16)

  // ---- resident weight fragments ----
  bf16x8_t whh_v[3][5];
  bf16x8_t wih_v[3];
  #pragma unroll
  for (int g = 0; g < 3; ++g) {
    #pragma unroll
    for (int kt = 0; kt < 5; ++kt)
      whh_v[g][kt] = *(const bf16x8_t*)(whh_f + ((size_t)((q * 3 + g) * 5 + kt) * 64 + lane) * 8);
    wih_v[g] = *(const bf16x8_t*)(wih_f + ((size_t)(q * 3 + g) * 64 + lane) * 8);
  }
  const float b_r  = -LOG2E * (b_ih[col] + b_hh[col]);
  const float b_z  = -LOG2E * (b_ih[160 + col] + b_hh[160 + col]);
  const float b_ni = -2.f * LOG2E * b_ih[320 + col];
  const float b_nh = -2.f * LOG2E * b_hh[320 + col];
  const float w0r = -LOG2E * w_ih[(size_t)col * 32];
  const float w0z = -LOG2E * w_ih[(size_t)(160 + col) * 32];
  const float w0n = -2.f * LOG2E * w_ih[(size_t)(320 + col) * 32];

  float h = 0.f;
  const f32x4_t z4 = {0.f, 0.f, 0.f, 0.f};

  const float* xrow_base =
      X + ((size_t)(b0 + elA) * T_SZ) * C_CH + 33 + (g4 * 8);

  // ---- prologue: x(0) into regs, S(0) -> combine constants ----
  float xc[8];
  #pragma unroll
  for (int j = 0; j < 8; ++j) xc[j] = xrow_base[j];
  float cr, cz, cn, fl;
  {
    const float2 s0 = Sf[b0 + me];
    cr = fmaf(s0.x, w0r, b_r);
    cz = fmaf(s0.x, w0z, b_z);
    cn = fmaf(s0.x, w0n, b_ni);
    fl = s0.y;
  }
  __syncthreads();

  // ---- the recurrence ----
  for (int t = 0; t <= maxfi; ++t) {
    const int p = t & 1, pn = p ^ 1;
    const int tn = (t < maxfi) ? (t + 1) : maxfi;

    // 1. h A-frag reads (5 x b64-pair, broadcast, conflict-free)
    frag_u hf0, hf1, hf2, hf3, hf4;
    {
      const u32x2_t* hp = (const u32x2_t*)&hbuf[p][rb_u16];
      u32x2_t l0 = hp[0],  u0 = hp[1];
      u32x2_t l1 = hp[8],  u1 = hp[9];
      u32x2_t l2 = hp[16], u2 = hp[17];
      u32x2_t l3 = hp[24], u3 = hp[25];
      u32x2_t l4 = hp[32], u4 = hp[33];
      hf0.u = (u32x4_t){l0.x, l0.y, u0.x, u0.y};
      hf1.u = (u32x4_t){l1.x, l1.y, u1.x, u1.y};
      hf2.u = (u32x4_t){l2.x, l2.y, u2.x, u2.y};
      hf3.u = (u32x4_t){l3.x, l3.y, u3.x, u3.y};
      hf4.u = (u32x4_t){l4.x, l4.y, u4.x, u4.y};
    }

    // 2. gin = x(t) @ W_ih^T (covers ds_read latency)
    bf16x8_t xf; unsigned* xfu = (unsigned*)&xf;
    #pragma unroll
    for (int j = 0; j < 4; ++j) xfu[j] = cvt_pk_bf16(xc[2 * j], xc[2 * j + 1]);
    f32x4_t ginr = MFMA16(xf, wih_v[0], z4, 0, 0, 0);
    f32x4_t ginz = MFMA16(xf, wih_v[1], z4, 0, 0, 0);
    f32x4_t ginn = MFMA16(xf, wih_v[2], z4, 0, 0, 0);

    // 3. prefetch t+1 (x row + S entry)
    float xn[8];
    const float* xr = xrow_base + (size_t)tn * C_CH;
    #pragma unroll
    for (int j = 0; j < 8; ++j) xn[j] = xr[j];
    const float2 sn = Sf[(size_t)tn * B_SZ + b0 + me];

    // 4. 15 hh MFMAs, gin as C-input, 6 parallel chains
    __builtin_amdgcn_s_setprio(1);
    f32x4_t ra  = MFMA16(hf0.h, whh_v[0][0], ginr, 0, 0, 0);
    f32x4_t za  = MFMA16(hf0.h, whh_v[1][0], ginz, 0, 0, 0);
    f32x4_t nha = MFMA16(hf0.h, whh_v[2][0], z4,   0, 0, 0);
    f32x4_t rb  = MFMA16(hf2.h, whh_v[0][2], z4,   0, 0, 0);
    f32x4_t zb  = MFMA16(hf2.h, whh_v[1][2], z4,   0, 0, 0);
    f32x4_t nhb = MFMA16(hf3.h, whh_v[2][3], z4,   0, 0, 0);
    ra  = MFMA16(hf1.h, whh_v[0][1], ra,  0, 0, 0);
    za  = MFMA16(hf1.h, whh_v[1][1], za,  0, 0, 0);
    nha = MFMA16(hf1.h, whh_v[2][1], nha, 0, 0, 0);
    rb  = MFMA16(hf3.h, whh_v[0][3], rb,  0, 0, 0);
    zb  = MFMA16(hf3.h, whh_v[1][3], zb,  0, 0, 0);
    nhb = MFMA16(hf4.h, whh_v[2][4], nhb, 0, 0, 0);
    nha = MFMA16(hf2.h, whh_v[2][2], nha, 0, 0, 0);
    rb  = MFMA16(hf4.h, whh_v[0][4], rb,  0, 0, 0);
    zb  = MFMA16(hf4.h, whh_v[1][4], zb,  0, 0, 0);
    __builtin_amdgcn_s_setprio(0);

    // 5. combine: ONE entry per lane (acc reg 0 = element g4, this col)
    {
      const float pre_r = (ra[0] + rb[0]) + cr;
      const float rr = rcp_f(1.f + exp2_f(pre_r));
      const float pre_z = (za[0] + zb[0]) + cz;
      const float zz = rcp_f(1.f + exp2_f(pre_z));
      float u = (ginn[0] + cn) + rr * ((nha[0] + nhb[0]) + b_nh);
      u = fminf(u, 60.f);
      const float e = exp2_f(u);
      const float nn = (1.f - e) * rcp_f(1.f + e);
      const float upd = nn + zz * (h - nn);
      h = h + fl * (upd - h);
    }

    // 6. publish h (1x ds_write_b16) and roll prefetched state
    hbuf[pn][wA_u16] = (unsigned short)cvt_pk_bf16(h, h);
    cr = fmaf(sn.x, w0r, b_r);
    cz = fmaf(sn.x, w0z, b_z);
    cn = fmaf(sn.x, w0n, b_ni);
    fl = sn.y;
    #pragma unroll
    for (int j = 0; j < 8; ++j) xc[j] = xn[j];
    __syncthreads();
  }

  // ---- epilogue: h -> LDS, then out = lin_w @ h + lin_b ----
  hm[me][col] = h;
  __syncthreads();
  if (tid < M_ELEM * OUTD) {
    const int e = tid >> 5, o = tid & 31;
    const float4* lw = (const float4*)(lin_w + o * HID);
    const float4* hv = (const float4*)(&hm[e][0]);
    float a0 = 0.f, a1 = 0.f, a2 = 0.f, a3 = 0.f;
    #pragma unroll
    for (int k = 0; k < HID / 4; ++k) {
      float4 w = lw[k], hh = hv[k];
      a0 = fmaf(w.x, hh.x, a0); a1 = fmaf(w.y, hh.y, a1);
      a2 = fmaf(w.z, hh.z, a2); a3 = fmaf(w.w, hh.w, a3);
    }
    out[(size_t)(b0 + e) * OUTD + o] = lin_b[o] + (a0 + a1) + (a2 + a3);
  }
}

extern "C" void kernel_launch(void* const* d_in, const int* in_sizes, int n_in,
                              void* d_out, int out_size, void* d_ws, size_t ws_size,
                              hipStream_t stream) {
  const float* times = (const float*)d_in[0];
  const float* X     = (const float*)d_in[1];
  const int*   fidx  = (const int*)d_in[2];
  const float* w_ih  = (const float*)d_in[3];
  const float* w_hh  = (const float*)d_in[4];
  const float* b_ih  = (const float*)d_in[5];
  const float* b_hh  = (const float*)d_in[6];
  const float* lin_w = (const float*)d_in[7];
  const float* lin_b = (const float*)d_in[8];
  float* outp = (float*)d_out;

  unsigned char* obsb = (unsigned char*)d_ws + OBS_OFF;
  unsigned* anyv = (unsigned*)((char*)d_ws + ANY_OFF);
  float* xd0 = (float*)((char*)d_ws + XD0_OFF);
  float2* S = (float2*)((char*)d_ws + S_OFF);
  unsigned short* whh_f = (unsigned short*)((char*)d_ws + WHH_OFF);
  unsigned short* wih_f = (unsigned short*)((char*)d_ws + WIH_OFF);

  k_zero<<<1, 512, 0, stream>>>(anyv);
  k_prep<<<B_SZ, 256, 0, stream>>>(X, times, obsb, anyv, xd0);
  k_dt<<<B_SZ, 64, 0, stream>>>(obsb, anyv, xd0, fidx, S);
  k_pack<<<45, 256, 0, stream>>>(w_ih, w_hh, whh_f, wih_f);
  k_scan<<<NBLK, NTHR, 0, stream>>>(X, fidx, w_ih, b_ih, b_hh,
                                    lin_w, lin_b, S, whh_f, wih_f, outp);
}

// Round 13
// 405.257 us; speedup vs baseline: 1.9376x; 1.3796x over previous
//
#include <hip/hip_runtime.h>
#include <math.h>

#define B_SZ 1024
#define T_SZ 512
#define C_CH 65
#define HID  160
#define OUTD 32
#define M_ELEM 4
#define NBLK 256          // B_SZ / M_ELEM -> one block per CU
#define NTHR 640          // 10 waves

#define LOG2E 1.4426950408889634f

// workspace layout (bytes)
#define OBS_OFF 0                    // 1024*512 = 512KB
#define ANY_OFF  524288              // 2KB
#define XD0_OFF  526336              // 2MB
#define S_OFF    2623488             // 4MB
#define WHH_OFF  6817792             // 153600B
#define WIH_OFF  6971392             // 30720B

typedef float f32x4_t __attribute__((ext_vector_type(4)));
typedef short bf16x8_t __attribute__((ext_vector_type(8)));
typedef unsigned u32x2_t __attribute__((ext_vector_type(2)));
typedef unsigned u32x4_t __attribute__((ext_vector_type(4)));
union frag_u { u32x4_t u; bf16x8_t h; };

__device__ __forceinline__ unsigned short f2bf(float x) {
  unsigned int u = __float_as_uint(x);
  unsigned int r = ((u >> 16) & 1u) + 0x7FFFu;
  return (unsigned short)((u + r) >> 16);
}
__device__ __forceinline__ unsigned cvt_pk_bf16(float lo, float hi) {
  unsigned r;
  asm("v_cvt_pk_bf16_f32 %0, %1, %2" : "=v"(r) : "v"(lo), "v"(hi));
  return r;
}
__device__ __forceinline__ float exp2_f(float x) {
  float r; asm("v_exp_f32 %0, %1" : "=v"(r) : "v"(x)); return r;
}
__device__ __forceinline__ float rcp_f(float x) {
  float r; asm("v_rcp_f32 %0, %1" : "=v"(r) : "v"(x)); return r;
}
// non-affine row offset (dwords): rows 0..3 -> {0,2,16,18}; with stride 96
// the (elem,g4) b64-pair read addresses cover distinct banks and the 4-lane
// same-address broadcast makes reads conflict-free (validated r11/r12).
__device__ __forceinline__ int tabf(int r) {
  return ((r & 1) << 1) | (((r >> 1) & 1) << 4);
}

// ---------------- phase 0: zero any-flags ----------------
__global__ void k_zero(unsigned* __restrict__ anyv) {
  int i = blockIdx.x * blockDim.x + threadIdx.x;
  if (i < T_SZ) anyv[i] = 0u;
}

// ---------------- phase 1: obs + any + Xd0 ----------------
__global__ __launch_bounds__(256) void k_prep(const float* __restrict__ X,
                                              const float* __restrict__ times,
                                              unsigned char* __restrict__ obs,
                                              unsigned* __restrict__ anyv,
                                              float* __restrict__ xd0) {
  const int b = blockIdx.x;
  const float* Xb = X + (size_t)b * T_SZ * C_CH;
  for (int t = threadIdx.x; t < T_SZ; t += 256) {
    const float* cur = Xb + t * C_CH;
    const float* prv = cur - C_CH;
    float m = -1e30f;
    if (t == 0) {
      #pragma unroll
      for (int c = 1; c <= 32; ++c) m = fmaxf(m, cur[c]);
    } else {
      #pragma unroll
      for (int c = 1; c <= 32; ++c) m = fmaxf(m, cur[c] - prv[c]);
    }
    unsigned char o = (m > 0.5f) ? (unsigned char)1 : (unsigned char)0;
    obs[(size_t)b * T_SZ + t] = o;
    if (o) atomicOr(&anyv[t], 1u);
    xd0[(size_t)b * T_SZ + t] = cur[0] - times[(t == 0) ? 0 : (t - 1)];
  }
}

// ---------------- phase 1b: per-element dt prefix + flag table -----------
__global__ __launch_bounds__(64) void k_dt(const unsigned char* __restrict__ obs,
                                           const unsigned* __restrict__ anyv,
                                           const float* __restrict__ xd0,
                                           const int* __restrict__ fidx,
                                           float2* __restrict__ S) {
  const int b = blockIdx.x;
  const int lane = threadIdx.x;
  const int t0 = lane * 8;
  const unsigned long long o8 =
      *(const unsigned long long*)(obs + (size_t)b * T_SZ + t0);
  const float4* xd4 = (const float4*)(xd0 + (size_t)b * T_SZ + t0);
  const float4 xa = xd4[0], xb = xd4[1];
  const uint4* av4 = (const uint4*)(anyv + t0);
  const uint4 aa = av4[0], ab = av4[1];
  const int fi = fidx[b];
  const float xv[8] = {xa.x, xa.y, xa.z, xa.w, xb.x, xb.y, xb.z, xb.w};
  const unsigned av[8] = {aa.x, aa.y, aa.z, aa.w, ab.x, ab.y, ab.z, ab.w};
  float run = 0.f;
  float dtl[8], fl[8];
  #pragma unroll
  for (int j = 0; j < 8; ++j) {
    const int o = (int)((o8 >> (8 * j)) & 0xffULL);
    const int any = (int)av[j];
    dtl[j] = run;
    if (any && !o) run += xv[j];
    fl[j] = (any && o && (t0 + j) <= fi) ? 1.f : 0.f;
  }
  float inc = run;
  #pragma unroll
  for (int off = 1; off < 64; off <<= 1) {
    float u = __shfl_up(inc, off, 64);
    if (lane >= off) inc += u;
  }
  const float excl = inc - run;
  #pragma unroll
  for (int j = 0; j < 8; ++j)
    S[(size_t)(t0 + j) * B_SZ + b] = make_float2(excl + dtl[j], fl[j]);
}

// ---------------- phase 1c: pack PRESCALED weights into bf16 B-frags -----
__global__ __launch_bounds__(256) void k_pack(const float* __restrict__ w_ih,
                                              const float* __restrict__ w_hh,
                                              unsigned short* __restrict__ whh_f,
                                              unsigned short* __restrict__ wih_f) {
  int i = blockIdx.x * 256 + threadIdx.x;
  if (i < 9600) {
    int l = i & 63; int kt = (i >> 6) % 5; int g = (i / 320) % 3; int q = i / 960;
    const float scl = (g < 2) ? -LOG2E : -2.f * LOG2E;
    int row = g * 160 + q * 16 + (l & 15);
    const float* src = w_hh + (size_t)row * HID + kt * 32 + (l >> 4) * 8;
    unsigned short* dst = whh_f + (size_t)i * 8;
    #pragma unroll
    for (int j = 0; j < 8; ++j) dst[j] = f2bf(scl * src[j]);
  } else if (i < 11520) {
    int i2 = i - 9600;
    int l = i2 & 63; int g = (i2 >> 6) % 3; int q = i2 / 192;
    const float scl = (g < 2) ? -LOG2E : -2.f * LOG2E;
    int row = g * 160 + q * 16 + (l & 15);
    const float* src = w_ih + (size_t)row * 32 + (l >> 4) * 8;
    unsigned short* dst = wih_f + (size_t)i2 * 8;
    #pragma unroll
    for (int j = 0; j < 8; ++j) dst[j] = f2bf(scl * src[j]);
  }
}

#define MFMA16 __builtin_amdgcn_mfma_f32_16x16x32_bf16

// ---------------- phase 2: batched MFMA recurrence ------------------------
// r12 structure (M=4, 10 waves, tabf LDS layout, 1 combine entry/lane,
// plain __syncthreads) + DEPTH-2 global prefetch: x/S issued at step t are
// consumed at t+2, so VMEM latency is covered by ~2 full steps and no step
// drains vmcnt at its boundary. Even/odd unrolled body keeps all pipeline
// buffer indices compile-time.
__global__ __launch_bounds__(NTHR) void k_scan(
    const float* __restrict__ X, const int* __restrict__ fidx,
    const float* __restrict__ w_ih,
    const float* __restrict__ b_ih, const float* __restrict__ b_hh,
    const float* __restrict__ lin_w, const float* __restrict__ lin_b,
    const float2* __restrict__ Sf,
    const unsigned short* __restrict__ whh_f, const unsigned short* __restrict__ wih_f,
    float* __restrict__ out)
{
  const int b0 = blockIdx.x * M_ELEM;
  const int tid = threadIdx.x;
  const int wid = tid >> 6;
  const int lane = tid & 63;
  const int q = wid;

  __shared__ __align__(16) unsigned short hbuf[2][800];   // bf16 h dbuf (tabf rows)
  __shared__ __align__(16) float hm[M_ELEM][HID];

  { unsigned* hz = (unsigned*)hbuf;
    for (int i = tid; i < 800; i += NTHR) hz[i] = 0u; }

  int maxfi = 0;
  #pragma unroll
  for (int e = 0; e < M_ELEM; ++e) maxfi = max(maxfi, fidx[b0 + e]);

  const int r16 = lane & 15;
  const int g4 = lane >> 4;
  // A-frag row -> element (permuted duplication): acc reg 0 of every lane is
  // the unique real (element=g4, col) pair.
  const int elA = ((r16 >> 2) + (r16 & 3)) & 3;
  const int me = g4;

  // LDS addresses
  const int rb_u16 = (elA * 96 + tabf(elA)) * 2 + g4 * 8;          // read base (u16)
  const int col = q * 16 + r16;
  const int wA_u16 = (g4 * 96 + tabf(g4)) * 2 + col;               // write (u16)

  // ---- resident weight fragments ----
  bf16x8_t whh_v[3][5];
  bf16x8_t wih_v[3];
  #pragma unroll
  for (int g = 0; g < 3; ++g) {
    #pragma unroll
    for (int kt = 0; kt < 5; ++kt)
      whh_v[g][kt] = *(const bf16x8_t*)(whh_f + ((size_t)((q * 3 + g) * 5 + kt) * 64 + lane) * 8);
    wih_v[g] = *(const bf16x8_t*)(wih_f + ((size_t)(q * 3 + g) * 64 + lane) * 8);
  }
  const float b_r  = -LOG2E * (b_ih[col] + b_hh[col]);
  const float b_z  = -LOG2E * (b_ih[160 + col] + b_hh[160 + col]);
  const float b_ni = -2.f * LOG2E * b_ih[320 + col];
  const float b_nh = -2.f * LOG2E * b_hh[320 + col];
  const float w0r = -LOG2E * w_ih[(size_t)col * 32];
  const float w0z = -LOG2E * w_ih[(size_t)(160 + col) * 32];
  const float w0n = -2.f * LOG2E * w_ih[(size_t)(320 + col) * 32];

  float h = 0.f;
  const f32x4_t z4 = {0.f, 0.f, 0.f, 0.f};

  const float* xrow_base =
      X + ((size_t)(b0 + elA) * T_SZ) * C_CH + 33 + (g4 * 8);

  // ---- prologue: xf for t=0; depth-2 buffers hold x/S for t=1 and t=2 ----
  bf16x8_t xf0, xf1;
  {
    float x0[8];
    #pragma unroll
    for (int j = 0; j < 8; ++j) x0[j] = xrow_base[j];
    unsigned* xu = (unsigned*)&xf0;
    #pragma unroll
    for (int j = 0; j < 4; ++j) xu[j] = cvt_pk_bf16(x0[2 * j], x0[2 * j + 1]);
  }
  float xb[2][8];
  float2 sb[2];
  {
    const int t1 = (1 <= maxfi) ? 1 : 0;
    const int t2 = (2 <= maxfi) ? 2 : maxfi;
    const float* xr1 = xrow_base + (size_t)t1 * C_CH;
    const float* xr2 = xrow_base + (size_t)t2 * C_CH;
    #pragma unroll
    for (int j = 0; j < 8; ++j) { xb[0][j] = xr1[j]; xb[1][j] = xr2[j]; }
    sb[0] = Sf[(size_t)t1 * B_SZ + b0 + me];
    sb[1] = Sf[(size_t)t2 * B_SZ + b0 + me];
  }
  float cr0, cz0, cn0, fl0, cr1, cz1, cn1, fl1;
  {
    const float2 s0 = Sf[b0 + me];
    cr0 = fmaf(s0.x, w0r, b_r);
    cz0 = fmaf(s0.x, w0z, b_z);
    cn0 = fmaf(s0.x, w0n, b_ni);
    fl0 = s0.y;
  }
  __syncthreads();

  const int NSTEP = (maxfi + 2) & ~1;   // even, >= maxfi+1; extra step is
                                        // fl-gated (S.fl=0 past fi) -> safe

// one recurrence step; PB = T&1 (compile-time), XFI/XFO = xf regs,
// C*I = combine constants for step T, C*O = produced for step T+1
#define BODY(T, PB, XFI, XFO, crI, czI, cnI, flI, crO, czO, cnO, flO)      \
  {                                                                        \
    /* 1. h A-frag reads (broadcast, conflict-free) */                     \
    frag_u hf0, hf1, hf2, hf3, hf4;                                        \
    {                                                                      \
      const u32x2_t* hp = (const u32x2_t*)&hbuf[PB][rb_u16];               \
      u32x2_t l0 = hp[0],  u0 = hp[1];                                     \
      u32x2_t l1 = hp[8],  u1 = hp[9];                                     \
      u32x2_t l2 = hp[16], u2 = hp[17];                                    \
      u32x2_t l3 = hp[24], u3 = hp[25];                                    \
      u32x2_t l4 = hp[32], u4 = hp[33];                                    \
      hf0.u = (u32x4_t){l0.x, l0.y, u0.x, u0.y};                           \
      hf1.u = (u32x4_t){l1.x, l1.y, u1.x, u1.y};                           \
      hf2.u = (u32x4_t){l2.x, l2.y, u2.x, u2.y};                           \
      hf3.u = (u32x4_t){l3.x, l3.y, u3.x, u3.y};                           \
      hf4.u = (u32x4_t){l4.x, l4.y, u4.x, u4.y};                           \
    }                                                                      \
    /* 2. gin MFMAs (x(T), converted a step ago; covers ds_read latency) */\
    f32x4_t ginr = MFMA16(XFI, wih_v[0], z4, 0, 0, 0);                     \
    f32x4_t ginz = MFMA16(XFI, wih_v[1], z4, 0, 0, 0);                     \
    f32x4_t ginn = MFMA16(XFI, wih_v[2], z4, 0, 0, 0);                     \
    /* 3. 15 hh MFMAs, gin as C-input, 6 parallel chains */                \
    __builtin_amdgcn_s_setprio(1);                                         \
    f32x4_t ra  = MFMA16(hf0.h, whh_v[0][0], ginr, 0, 0, 0);               \
    f32x4_t za  = MFMA16(hf0.h, whh_v[1][0], ginz, 0, 0, 0);               \
    f32x4_t nha = MFMA16(hf0.h, whh_v[2][0], z4,   0, 0, 0);               \
    f32x4_t rb  = MFMA16(hf2.h, whh_v[0][2], z4,   0, 0, 0);               \
    f32x4_t zb  = MFMA16(hf2.h, whh_v[1][2], z4,   0, 0, 0);               \
    f32x4_t nhb = MFMA16(hf3.h, whh_v[2][3], z4,   0, 0, 0);               \
    ra  = MFMA16(hf1.h, whh_v[0][1], ra,  0, 0, 0);                        \
    za  = MFMA16(hf1.h, whh_v[1][1], za,  0, 0, 0);                        \
    nha = MFMA16(hf1.h, whh_v[2][1], nha, 0, 0, 0);                        \
    rb  = MFMA16(hf3.h, whh_v[0][3], rb,  0, 0, 0);                        \
    zb  = MFMA16(hf3.h, whh_v[1][3], zb,  0, 0, 0);                        \
    nhb = MFMA16(hf4.h, whh_v[2][4], nhb, 0, 0, 0);                        \
    nha = MFMA16(hf2.h, whh_v[2][2], nha, 0, 0, 0);                        \
    rb  = MFMA16(hf4.h, whh_v[0][4], rb,  0, 0, 0);                        \
    zb  = MFMA16(hf4.h, whh_v[1][4], zb,  0, 0, 0);                        \
    __builtin_amdgcn_s_setprio(0);                                         \
    /* 4. consume depth-2 prefetch: xf and constants for step T+1 */       \
    {                                                                      \
      unsigned* xu = (unsigned*)&XFO;                                      \
      xu[0] = cvt_pk_bf16(xb[PB][0], xb[PB][1]);                           \
      xu[1] = cvt_pk_bf16(xb[PB][2], xb[PB][3]);                           \
      xu[2] = cvt_pk_bf16(xb[PB][4], xb[PB][5]);                           \
      xu[3] = cvt_pk_bf16(xb[PB][6], xb[PB][7]);                           \
    }                                                                      \
    crO = fmaf(sb[PB].x, w0r, b_r);                                        \
    czO = fmaf(sb[PB].x, w0z, b_z);                                        \
    cnO = fmaf(sb[PB].x, w0n, b_ni);                                       \
    flO = sb[PB].y;                                                        \
    /* 5. issue loads for step T+3 into the freed buffer */                \
    {                                                                      \
      const int tl = min((T) + 3, T_SZ - 1);                               \
      const float* xr = xrow_base + (size_t)tl * C_CH;                     \
      _Pragma("unroll")                                                    \
      for (int j = 0; j < 8; ++j) xb[PB][j] = xr[j];                       \
      sb[PB] = Sf[(size_t)tl * B_SZ + b0 + me];                            \
    }                                                                      \
    /* 6. combine: one (element,col) entry per lane */                     \
    {                                                                      \
      const float pre_r = (ra[0] + rb[0]) + crI;                           \
      const float rr = rcp_f(1.f + exp2_f(pre_r));                         \
      const float pre_z = (za[0] + zb[0]) + czI;                           \
      const float zz = rcp_f(1.f + exp2_f(pre_z));                         \
      float u = (ginn[0] + cnI) + rr * ((nha[0] + nhb[0]) + b_nh);         \
      u = fminf(u, 60.f);                                                  \
      const float e = exp2_f(u);                                           \
      const float nn = (1.f - e) * rcp_f(1.f + e);                         \
      const float upd = nn + zz * (h - nn);                                \
      h = h + flI * (upd - h);                                             \
    }                                                                      \
    /* 7. publish h and barrier */                                         \
    hbuf[PB ^ 1][wA_u16] = (unsigned short)cvt_pk_bf16(h, h);              \
    __syncthreads();                                                       \
  }

  for (int t = 0; t < NSTEP; t += 2) {
    BODY(t,     0, xf0, xf1, cr0, cz0, cn0, fl0, cr1, cz1, cn1, fl1);
    BODY(t + 1, 1, xf1, xf0, cr1, cz1, cn1, fl1, cr0, cz0, cn0, fl0);
  }
#undef BODY

  // ---- epilogue: h -> LDS, then out = lin_w @ h + lin_b ----
  hm[me][col] = h;
  __syncthreads();
  if (tid < M_ELEM * OUTD) {
    const int e = tid >> 5, o = tid & 31;
    const float4* lw = (const float4*)(lin_w + o * HID);
    const float4* hv = (const float4*)(&hm[e][0]);
    float a0 = 0.f, a1 = 0.f, a2 = 0.f, a3 = 0.f;
    #pragma unroll
    for (int k = 0; k < HID / 4; ++k) {
      float4 w = lw[k], hh = hv[k];
      a0 = fmaf(w.x, hh.x, a0); a1 = fmaf(w.y, hh.y, a1);
      a2 = fmaf(w.z, hh.z, a2); a3 = fmaf(w.w, hh.w, a3);
    }
    out[(size_t)(b0 + e) * OUTD + o] = lin_b[o] + (a0 + a1) + (a2 + a3);
  }
}

extern "C" void kernel_launch(void* const* d_in, const int* in_sizes, int n_in,
                              void* d_out, int out_size, void* d_ws, size_t ws_size,
                              hipStream_t stream) {
  const float* times = (const float*)d_in[0];
  const float* X     = (const float*)d_in[1];
  const int*   fidx  = (const int*)d_in[2];
  const float* w_ih  = (const float*)d_in[3];
  const float* w_hh  = (const float*)d_in[4];
  const float* b_ih  = (const float*)d_in[5];
  const float* b_hh  = (const float*)d_in[6];
  const float* lin_w = (const float*)d_in[7];
  const float* lin_b = (const float*)d_in[8];
  float* outp = (float*)d_out;

  unsigned char* obsb = (unsigned char*)d_ws + OBS_OFF;
  unsigned* anyv = (unsigned*)((char*)d_ws + ANY_OFF);
  float* xd0 = (float*)((char*)d_ws + XD0_OFF);
  float2* S = (float2*)((char*)d_ws + S_OFF);
  unsigned short* whh_f = (unsigned short*)((char*)d_ws + WHH_OFF);
  unsigned short* wih_f = (unsigned short*)((char*)d_ws + WIH_OFF);

  k_zero<<<1, 512, 0, stream>>>(anyv);
  k_prep<<<B_SZ, 256, 0, stream>>>(X, times, obsb, anyv, xd0);
  k_dt<<<B_SZ, 64, 0, stream>>>(obsb, anyv, xd0, fidx, S);
  k_pack<<<45, 256, 0, stream>>>(w_ih, w_hh, whh_f, wih_f);
  k_scan<<<NBLK, NTHR, 0, stream>>>(X, fidx, w_ih, b_ih, b_hh,
                                    lin_w, lin_b, S, whh_f, wih_f, outp);
}

// Round 14
// 367.193 us; speedup vs baseline: 2.1385x; 1.1037x over previous
//
#include <hip/hip_runtime.h>
#include <math.h>

#define B_SZ 1024
#define T_SZ 512
#define C_CH 65
#define HID  160
#define OUTD 32
#define M_ELEM 4
#define NBLK 256          // B_SZ / M_ELEM -> one block per CU
#define NTHR 640          // 10 waves

#define LOG2E 1.4426950408889634f

// workspace layout (bytes)
#define OBS_OFF 0                    // 1024*512 = 512KB
#define ANY_OFF  524288              // 2KB
#define XD0_OFF  526336              // 2MB
#define S_OFF    2623488             // 4MB
#define WHH_OFF  6817792             // 153600B
#define WIH_OFF  6971392             // 30720B
#define XPK_OFF  7002112             // 1024*512*32*2 = 32MB (bf16 x-slices)

typedef float f32x4_t __attribute__((ext_vector_type(4)));
typedef short bf16x8_t __attribute__((ext_vector_type(8)));
typedef unsigned u32x2_t __attribute__((ext_vector_type(2)));
typedef unsigned u32x4_t __attribute__((ext_vector_type(4)));
union frag_u { u32x4_t u; bf16x8_t h; };

__device__ __forceinline__ unsigned short f2bf(float x) {
  unsigned int u = __float_as_uint(x);
  unsigned int r = ((u >> 16) & 1u) + 0x7FFFu;
  return (unsigned short)((u + r) >> 16);
}
__device__ __forceinline__ unsigned cvt_pk_bf16(float lo, float hi) {
  unsigned r;
  asm("v_cvt_pk_bf16_f32 %0, %1, %2" : "=v"(r) : "v"(lo), "v"(hi));
  return r;
}
__device__ __forceinline__ float exp2_f(float x) {
  float r; asm("v_exp_f32 %0, %1" : "=v"(r) : "v"(x)); return r;
}
__device__ __forceinline__ float rcp_f(float x) {
  float r; asm("v_rcp_f32 %0, %1" : "=v"(r) : "v"(x)); return r;
}
// non-affine row offset (dwords): rows 0..3 -> {0,2,16,18}; with stride 96
// the (elem,g4) b64-pair read addresses cover distinct banks and the 4-lane
// same-address broadcast makes reads conflict-free (validated r11/r12).
__device__ __forceinline__ int tabf(int r) {
  return ((r & 1) << 1) | (((r >> 1) & 1) << 4);
}

// ---------------- phase 0: zero any-flags ----------------
__global__ void k_zero(unsigned* __restrict__ anyv) {
  int i = blockIdx.x * blockDim.x + threadIdx.x;
  if (i < T_SZ) anyv[i] = 0u;
}

// ---------------- phase 1: obs + any + Xd0 + bf16 x-pack ----------------
__global__ __launch_bounds__(256) void k_prep(const float* __restrict__ X,
                                              const float* __restrict__ times,
                                              unsigned char* __restrict__ obs,
                                              unsigned* __restrict__ anyv,
                                              float* __restrict__ xd0,
                                              unsigned short* __restrict__ xpk) {
  const int b = blockIdx.x;
  const float* Xb = X + (size_t)b * T_SZ * C_CH;
  for (int t = threadIdx.x; t < T_SZ; t += 256) {
    const float* cur = Xb + t * C_CH;
    const float* prv = cur - C_CH;
    float m = -1e30f;
    if (t == 0) {
      #pragma unroll
      for (int c = 1; c <= 32; ++c) m = fmaxf(m, cur[c]);
    } else {
      #pragma unroll
      for (int c = 1; c <= 32; ++c) m = fmaxf(m, cur[c] - prv[c]);
    }
    unsigned char o = (m > 0.5f) ? (unsigned char)1 : (unsigned char)0;
    obs[(size_t)b * T_SZ + t] = o;
    if (o) atomicOr(&anyv[t], 1u);
    xd0[(size_t)b * T_SZ + t] = cur[0] - times[(t == 0) ? 0 : (t - 1)];
    // pack channels 33..64 as bf16, 16B-aligned: xpk[b][t][32]
    unsigned short* dst = xpk + ((size_t)b * T_SZ + t) * 32;
    #pragma unroll
    for (int c = 0; c < 32; ++c) dst[c] = f2bf(cur[33 + c]);
  }
}

// ---------------- phase 1b: per-element dt prefix + flag table -----------
__global__ __launch_bounds__(64) void k_dt(const unsigned char* __restrict__ obs,
                                           const unsigned* __restrict__ anyv,
                                           const float* __restrict__ xd0,
                                           const int* __restrict__ fidx,
                                           float2* __restrict__ S) {
  const int b = blockIdx.x;
  const int lane = threadIdx.x;
  const int t0 = lane * 8;
  const unsigned long long o8 =
      *(const unsigned long long*)(obs + (size_t)b * T_SZ + t0);
  const float4* xd4 = (const float4*)(xd0 + (size_t)b * T_SZ + t0);
  const float4 xa = xd4[0], xb = xd4[1];
  const uint4* av4 = (const uint4*)(anyv + t0);
  const uint4 aa = av4[0], ab = av4[1];
  const int fi = fidx[b];
  const float xv[8] = {xa.x, xa.y, xa.z, xa.w, xb.x, xb.y, xb.z, xb.w};
  const unsigned av[8] = {aa.x, aa.y, aa.z, aa.w, ab.x, ab.y, ab.z, ab.w};
  float run = 0.f;
  float dtl[8], fl[8];
  #pragma unroll
  for (int j = 0; j < 8; ++j) {
    const int o = (int)((o8 >> (8 * j)) & 0xffULL);
    const int any = (int)av[j];
    dtl[j] = run;
    if (any && !o) run += xv[j];
    fl[j] = (any && o && (t0 + j) <= fi) ? 1.f : 0.f;
  }
  float inc = run;
  #pragma unroll
  for (int off = 1; off < 64; off <<= 1) {
    float u = __shfl_up(inc, off, 64);
    if (lane >= off) inc += u;
  }
  const float excl = inc - run;
  #pragma unroll
  for (int j = 0; j < 8; ++j)
    S[(size_t)(t0 + j) * B_SZ + b] = make_float2(excl + dtl[j], fl[j]);
}

// ---------------- phase 1c: pack PRESCALED weights into bf16 B-frags -----
__global__ __launch_bounds__(256) void k_pack(const float* __restrict__ w_ih,
                                              const float* __restrict__ w_hh,
                                              unsigned short* __restrict__ whh_f,
                                              unsigned short* __restrict__ wih_f) {
  int i = blockIdx.x * 256 + threadIdx.x;
  if (i < 9600) {
    int l = i & 63; int kt = (i >> 6) % 5; int g = (i / 320) % 3; int q = i / 960;
    const float scl = (g < 2) ? -LOG2E : -2.f * LOG2E;
    int row = g * 160 + q * 16 + (l & 15);
    const float* src = w_hh + (size_t)row * HID + kt * 32 + (l >> 4) * 8;
    unsigned short* dst = whh_f + (size_t)i * 8;
    #pragma unroll
    for (int j = 0; j < 8; ++j) dst[j] = f2bf(scl * src[j]);
  } else if (i < 11520) {
    int i2 = i - 9600;
    int l = i2 & 63; int g = (i2 >> 6) % 3; int q = i2 / 192;
    const float scl = (g < 2) ? -LOG2E : -2.f * LOG2E;
    int row = g * 160 + q * 16 + (l & 15);
    const float* src = w_ih + (size_t)row * 32 + (l >> 4) * 8;
    unsigned short* dst = wih_f + (size_t)i2 * 8;
    #pragma unroll
    for (int j = 0; j < 8; ++j) dst[j] = f2bf(scl * src[j]);
  }
}

#define MFMA16 __builtin_amdgcn_mfma_f32_16x16x32_bf16

// ---------------- phase 2: batched MFMA recurrence ------------------------
// r13 structure (M=4, 10 waves, tabf LDS layout, 1 combine entry/lane,
// depth-2 prefetch, even/odd unroll, plain __syncthreads) with the x path
// replaced by the pre-packed bf16 table: one aligned global_load_dwordx4
// per lane per step straight into the MFMA A-frag, no cvt, no scalar loads.
__global__ __launch_bounds__(NTHR) void k_scan(
    const unsigned short* __restrict__ xpk, const int* __restrict__ fidx,
    const float* __restrict__ w_ih,
    const float* __restrict__ b_ih, const float* __restrict__ b_hh,
    const float* __restrict__ lin_w, const float* __restrict__ lin_b,
    const float2* __restrict__ Sf,
    const unsigned short* __restrict__ whh_f, const unsigned short* __restrict__ wih_f,
    float* __restrict__ out)
{
  const int b0 = blockIdx.x * M_ELEM;
  const int tid = threadIdx.x;
  const int wid = tid >> 6;
  const int lane = tid & 63;
  const int q = wid;

  __shared__ __align__(16) unsigned short hbuf[2][800];   // bf16 h dbuf (tabf rows)
  __shared__ __align__(16) float hm[M_ELEM][HID];

  { unsigned* hz = (unsigned*)hbuf;
    for (int i = tid; i < 800; i += NTHR) hz[i] = 0u; }

  int maxfi = 0;
  #pragma unroll
  for (int e = 0; e < M_ELEM; ++e) maxfi = max(maxfi, fidx[b0 + e]);

  const int r16 = lane & 15;
  const int g4 = lane >> 4;
  // A-frag row -> element (permuted duplication): acc reg 0 of every lane is
  // the unique real (element=g4, col) pair.
  const int elA = ((r16 >> 2) + (r16 & 3)) & 3;
  const int me = g4;

  // LDS addresses
  const int rb_u16 = (elA * 96 + tabf(elA)) * 2 + g4 * 8;          // read base (u16)
  const int col = q * 16 + r16;
  const int wA_u16 = (g4 * 96 + tabf(g4)) * 2 + col;               // write (u16)

  // ---- resident weight fragments ----
  bf16x8_t whh_v[3][5];
  bf16x8_t wih_v[3];
  #pragma unroll
  for (int g = 0; g < 3; ++g) {
    #pragma unroll
    for (int kt = 0; kt < 5; ++kt)
      whh_v[g][kt] = *(const bf16x8_t*)(whh_f + ((size_t)((q * 3 + g) * 5 + kt) * 64 + lane) * 8);
    wih_v[g] = *(const bf16x8_t*)(wih_f + ((size_t)(q * 3 + g) * 64 + lane) * 8);
  }
  const float b_r  = -LOG2E * (b_ih[col] + b_hh[col]);
  const float b_z  = -LOG2E * (b_ih[160 + col] + b_hh[160 + col]);
  const float b_ni = -2.f * LOG2E * b_ih[320 + col];
  const float b_nh = -2.f * LOG2E * b_hh[320 + col];
  const float w0r = -LOG2E * w_ih[(size_t)col * 32];
  const float w0z = -LOG2E * w_ih[(size_t)(160 + col) * 32];
  const float w0n = -2.f * LOG2E * w_ih[(size_t)(320 + col) * 32];

  float h = 0.f;
  const f32x4_t z4 = {0.f, 0.f, 0.f, 0.f};

  // per-lane bf16 x-frag source: xpk[b0+elA][t][g4*8 .. +8]
  const unsigned short* xpk_base =
      xpk + ((size_t)(b0 + elA) * T_SZ) * 32 + g4 * 8;

  // ---- prologue: x frags for t=0 (current) and t=1 (pipe), S for 0/1 ----
  bf16x8_t xe = *(const bf16x8_t*)(xpk_base);
  bf16x8_t xo = *(const bf16x8_t*)(xpk_base + (size_t)min(1, maxfi) * 32);
  float2 se = Sf[b0 + me];
  float2 so = Sf[(size_t)min(1, maxfi) * B_SZ + b0 + me];
  __syncthreads();

  const int NSTEP = (maxfi + 2) & ~1;   // even, >= maxfi+1; extra step is
                                        // fl-gated (S.fl=0 past fi) -> safe

// one recurrence step; PB = T&1 (compile-time). XI = x frag for step T
// (reloaded here with x(T+2), consumed again at step T+2 -> depth-2 cover).
// SI likewise.
#define BODY(T, PB, XI, SI)                                                \
  {                                                                        \
    /* 1. h A-frag reads (broadcast, conflict-free) */                     \
    frag_u hf0, hf1, hf2, hf3, hf4;                                        \
    {                                                                      \
      const u32x2_t* hp = (const u32x2_t*)&hbuf[PB][rb_u16];               \
      u32x2_t l0 = hp[0],  u0 = hp[1];                                     \
      u32x2_t l1 = hp[8],  u1 = hp[9];                                     \
      u32x2_t l2 = hp[16], u2 = hp[17];                                    \
      u32x2_t l3 = hp[24], u3 = hp[25];                                    \
      u32x2_t l4 = hp[32], u4 = hp[33];                                    \
      hf0.u = (u32x4_t){l0.x, l0.y, u0.x, u0.y};                           \
      hf1.u = (u32x4_t){l1.x, l1.y, u1.x, u1.y};                           \
      hf2.u = (u32x4_t){l2.x, l2.y, u2.x, u2.y};                           \
      hf3.u = (u32x4_t){l3.x, l3.y, u3.x, u3.y};                           \
      hf4.u = (u32x4_t){l4.x, l4.y, u4.x, u4.y};                           \
    }                                                                      \
    /* 2. gin MFMAs (x(T), prepacked bf16; covers ds_read latency) */      \
    f32x4_t ginr = MFMA16(XI, wih_v[0], z4, 0, 0, 0);                      \
    f32x4_t ginz = MFMA16(XI, wih_v[1], z4, 0, 0, 0);                      \
    f32x4_t ginn = MFMA16(XI, wih_v[2], z4, 0, 0, 0);                      \
    /* 3. combine constants for this step (off the MFMA pipe) */           \
    const float crI = fmaf(SI.x, w0r, b_r);                                \
    const float czI = fmaf(SI.x, w0z, b_z);                                \
    const float cnI = fmaf(SI.x, w0n, b_ni);                               \
    const float flI = SI.y;                                                \
    /* 4. 15 hh MFMAs, gin as C-input, 6 parallel chains */                \
    __builtin_amdgcn_s_setprio(1);                                         \
    f32x4_t ra  = MFMA16(hf0.h, whh_v[0][0], ginr, 0, 0, 0);               \
    f32x4_t za  = MFMA16(hf0.h, whh_v[1][0], ginz, 0, 0, 0);               \
    f32x4_t nha = MFMA16(hf0.h, whh_v[2][0], z4,   0, 0, 0);               \
    f32x4_t rb  = MFMA16(hf2.h, whh_v[0][2], z4,   0, 0, 0);               \
    f32x4_t zb  = MFMA16(hf2.h, whh_v[1][2], z4,   0, 0, 0);               \
    f32x4_t nhb = MFMA16(hf3.h, whh_v[2][3], z4,   0, 0, 0);               \
    ra  = MFMA16(hf1.h, whh_v[0][1], ra,  0, 0, 0);                        \
    za  = MFMA16(hf1.h, whh_v[1][1], za,  0, 0, 0);                        \
    nha = MFMA16(hf1.h, whh_v[2][1], nha, 0, 0, 0);                        \
    rb  = MFMA16(hf3.h, whh_v[0][3], rb,  0, 0, 0);                        \
    zb  = MFMA16(hf3.h, whh_v[1][3], zb,  0, 0, 0);                        \
    nhb = MFMA16(hf4.h, whh_v[2][4], nhb, 0, 0, 0);                        \
    nha = MFMA16(hf2.h, whh_v[2][2], nha, 0, 0, 0);                        \
    rb  = MFMA16(hf4.h, whh_v[0][4], rb,  0, 0, 0);                        \
    zb  = MFMA16(hf4.h, whh_v[1][4], zb,  0, 0, 0);                        \
    __builtin_amdgcn_s_setprio(0);                                         \
    /* 5. issue loads for step T+2 into the just-consumed regs */          \
    {                                                                      \
      const int tl = min((T) + 2, T_SZ - 1);                               \
      XI = *(const bf16x8_t*)(xpk_base + (size_t)tl * 32);                 \
      SI = Sf[(size_t)tl * B_SZ + b0 + me];                                \
    }                                                                      \
    /* 6. combine: one (element,col) entry per lane */                     \
    {                                                                      \
      const float pre_r = (ra[0] + rb[0]) + crI;                           \
      const float rr = rcp_f(1.f + exp2_f(pre_r));                         \
      const float pre_z = (za[0] + zb[0]) + czI;                           \
      const float zz = rcp_f(1.f + exp2_f(pre_z));                         \
      float u = (ginn[0] + cnI) + rr * ((nha[0] + nhb[0]) + b_nh);         \
      u = fminf(u, 60.f);                                                  \
      const float e = exp2_f(u);                                           \
      const float nn = (1.f - e) * rcp_f(1.f + e);                         \
      const float upd = nn + zz * (h - nn);                                \
      h = h + flI * (upd - h);                                             \
    }                                                                      \
    /* 7. publish h and barrier */                                         \
    hbuf[PB ^ 1][wA_u16] = (unsigned short)cvt_pk_bf16(h, h);              \
    __syncthreads();                                                       \
  }

  for (int t = 0; t < NSTEP; t += 2) {
    BODY(t,     0, xe, se);
    BODY(t + 1, 1, xo, so);
  }
#undef BODY

  // ---- epilogue: h -> LDS, then out = lin_w @ h + lin_b ----
  hm[me][col] = h;
  __syncthreads();
  if (tid < M_ELEM * OUTD) {
    const int e = tid >> 5, o = tid & 31;
    const float4* lw = (const float4*)(lin_w + o * HID);
    const float4* hv = (const float4*)(&hm[e][0]);
    float a0 = 0.f, a1 = 0.f, a2 = 0.f, a3 = 0.f;
    #pragma unroll
    for (int k = 0; k < HID / 4; ++k) {
      float4 w = lw[k], hh = hv[k];
      a0 = fmaf(w.x, hh.x, a0); a1 = fmaf(w.y, hh.y, a1);
      a2 = fmaf(w.z, hh.z, a2); a3 = fmaf(w.w, hh.w, a3);
    }
    out[(size_t)(b0 + e) * OUTD + o] = lin_b[o] + (a0 + a1) + (a2 + a3);
  }
}

extern "C" void kernel_launch(void* const* d_in, const int* in_sizes, int n_in,
                              void* d_out, int out_size, void* d_ws, size_t ws_size,
                              hipStream_t stream) {
  const float* times = (const float*)d_in[0];
  const float* X     = (const float*)d_in[1];
  const int*   fidx  = (const int*)d_in[2];
  const float* w_ih  = (const float*)d_in[3];
  const float* w_hh  = (const float*)d_in[4];
  const float* b_ih  = (const float*)d_in[5];
  const float* b_hh  = (const float*)d_in[6];
  const float* lin_w = (const float*)d_in[7];
  const float* lin_b = (const float*)d_in[8];
  float* outp = (float*)d_out;

  unsigned char* obsb = (unsigned char*)d_ws + OBS_OFF;
  unsigned* anyv = (unsigned*)((char*)d_ws + ANY_OFF);
  float* xd0 = (float*)((char*)d_ws + XD0_OFF);
  float2* S = (float2*)((char*)d_ws + S_OFF);
  unsigned short* whh_f = (unsigned short*)((char*)d_ws + WHH_OFF);
  unsigned short* wih_f = (unsigned short*)((char*)d_ws + WIH_OFF);
  unsigned short* xpk = (unsigned short*)((char*)d_ws + XPK_OFF);

  k_zero<<<1, 512, 0, stream>>>(anyv);
  k_prep<<<B_SZ, 256, 0, stream>>>(X, times, obsb, anyv, xd0, xpk);
  k_dt<<<B_SZ, 64, 0, stream>>>(obsb, anyv, xd0, fidx, S);
  k_pack<<<45, 256, 0, stream>>>(w_ih, w_hh, whh_f, wih_f);
  k_scan<<<NBLK, NTHR, 0, stream>>>(xpk, fidx, w_ih, b_ih, b_hh,
                                    lin_w, lin_b, S, whh_f, wih_f, outp);
}